// Round 6
// baseline (154.224 us; speedup 1.0000x reference)
//
#include <hip/hip_runtime.h>
#include <hip/hip_fp16.h>

#define TAU 0.07f
#define MARGIN 0.2f
#define NSPEC 64
#define BB 8192
#define DD 256

// ---------------- ws layout (bytes) ----------------
// zeroed-by-k1 region: [0, 133120)
//   0      float scalars[8] [0]=triSum [1]=infoSum [2]=n_valid [3]=n_valid_i
//                           [4]=doneCnt(int,k67) [5]=arriveCnt(int,k2)
//   288    int   counts[64]
//   544    int   offsets[64]
//   1024   float lseRow[B]
//   33792  float lseCol[B]
//   66560  float Ts[64*256]   (atomic-accumulated)
//   132096 float T[256]
// unzeroed:
//   133632 float diag[B]
//   166400 int   memberList[B]
//   199168 float tri[B]
#define WS_SCALARS   0
#define WS_COUNTS    288
#define WS_OFFSETS   544
#define WS_LSEROW    1024
#define WS_LSECOL    33792
#define WS_TS        66560
#define WS_T         132096
#define WS_ZERO_BYTES 133120   // 8320 float4
#define WS_DIAG      133632
#define WS_MEMBER    166400
#define WS_TRI       199168

typedef _Float16 half8 __attribute__((ext_vector_type(8)));
typedef float float4v __attribute__((ext_vector_type(4)));
typedef unsigned int uint4v __attribute__((ext_vector_type(4)));

#define NB5 512          // k5-role blocks in fused k45 (species x 4 rt x 2 ct)
#define NB45 (NB5 + BB/4)

__device__ __forceinline__ uint4v pack8(float4 a, float4 b) {
  half8 h;
  h[0] = (_Float16)a.x; h[1] = (_Float16)a.y; h[2] = (_Float16)a.z; h[3] = (_Float16)a.w;
  h[4] = (_Float16)b.x; h[5] = (_Float16)b.y; h[6] = (_Float16)b.z; h[7] = (_Float16)b.w;
  return __builtin_bit_cast(uint4v, h);
}

// ---- k1_all: zero accumulators + counts + scan + scatter + valid-counts ----
__global__ void k1_all(const int* __restrict__ ids, char* ws, int* counts_g,
                       int* offsets_g, int* memberList, float* scalars) {
  __shared__ int cnt[NSPEC];
  __shared__ int off[NSPEC];
  int tid = threadIdx.x;
  float4* z = (float4*)ws;
  float4 z4 = make_float4(0.f, 0.f, 0.f, 0.f);
  for (int u = tid; u < WS_ZERO_BYTES / 16; u += 1024) z[u] = z4;
  if (tid < NSPEC) cnt[tid] = 0;
  __syncthreads();
  int myS[8], myP[8];
  #pragma unroll
  for (int r = 0; r < 8; ++r) {
    int i = r * 1024 + tid;
    int s = ids[i];
    myS[r] = s;
    myP[r] = atomicAdd(&cnt[s], 1);
  }
  __syncthreads();
  if (tid < NSPEC) {  // exactly wave 0
    int o = 0;
    for (int t = 0; t < NSPEC; ++t) o += (t < tid) ? cnt[t] : 0;
    off[tid] = o;
    offsets_g[tid] = o;
    int c = cnt[tid];
    counts_g[tid] = c;
    unsigned long long bv = __ballot(c >= 2);
    float nvi = (c >= 2 && c <= BB - 1) ? (float)c : 0.f;
    for (int o2 = 1; o2 < 64; o2 <<= 1) nvi += __shfl_xor(nvi, o2);
    if (tid == 0) {
      scalars[2] = (float)__popcll(bv);
      scalars[3] = nvi;
    }
  }
  __syncthreads();
  #pragma unroll
  for (int r = 0; r < 8; ++r) {
    int i = r * 1024 + tid;
    memberList[off[myS[r]] + myP[r]] = i;
  }
}

// ---- k2: per-species text sums Ts[s][d]; last-arriving block reduces Ts->T ----
__global__ void k2_ts(const float* __restrict__ tx, const int* __restrict__ counts,
                      const int* __restrict__ offsets, const int* __restrict__ memberList,
                      float* Ts, float* T, float* scalars) {
  int s = blockIdx.x, r = blockIdx.y;
  int m = counts[s], g0 = offsets[s];
  int k0 = (m * r) >> 3, k1 = (m * (r + 1)) >> 3;
  int d = threadIdx.x;
  if (k0 < k1) {
    float acc = 0.f;
    for (int k = k0; k < k1; ++k) acc += tx[memberList[g0 + k] * DD + d];
    atomicAdd(&Ts[s * DD + d], acc);
  }
  // arrival counter: last block computes T from completed Ts
  __threadfence();
  __syncthreads();
  __shared__ int last;
  if (d == 0) last = atomicAdd((int*)&scalars[5], 1);
  __syncthreads();
  if (last == NSPEC * 8 - 1) {
    const volatile float* ts = (const volatile float*)Ts;
    float acc = 0.f;
    for (int ss = 0; ss < NSPEC; ++ss) acc += ts[ss * DD + d];
    T[d] = acc;
  }
}

// ---- k45: fused. Blocks [0,NB5): per-species MFMA sum-of-exp (round-4 tiling).
//           Blocks [NB5,NB45): per-row diag/triplet (one wave per row). ----
__global__ void k45(const float* __restrict__ sp, const float* __restrict__ tx,
                    const int* __restrict__ ids, const int* __restrict__ counts,
                    const int* __restrict__ offsets, const int* __restrict__ memberList,
                    const float* __restrict__ Ts, const float* __restrict__ T,
                    float* diag, float* tri, float* lseRow, float* lseCol) {
  __shared__ uint4v lds5[1536];  // A: [0,512) ; B: [512,1536)  (24 KB, k5 path only)
  int tid = threadIdx.x;

  if (blockIdx.x >= NB5) {
    // ---------------- k4 path: 4 rows per block, one wave per row ----------------
    int gt = (blockIdx.x - NB5) * 256 + tid;
    int i = gt >> 6, lane = gt & 63;
    float4 a = *reinterpret_cast<const float4*>(sp + i * DD + lane * 4);
    float4 b = *reinterpret_cast<const float4*>(tx + i * DD + lane * 4);
    float4 tv = *reinterpret_cast<const float4*>(T + lane * 4);
    int s = ids[i];
    int m = counts[s];
    float4 c = *reinterpret_cast<const float4*>(Ts + s * DD + lane * 4);
    float dDiag = a.x * b.x + a.y * b.y + a.z * b.z + a.w * b.w;
    float dT    = a.x * tv.x + a.y * tv.y + a.z * tv.z + a.w * tv.w;
    float dTs   = a.x * c.x + a.y * c.y + a.z * c.z + a.w * c.w;
    #pragma unroll
    for (int o = 1; o < 64; o <<= 1) {
      dDiag += __shfl_xor(dDiag, o);
      dT    += __shfl_xor(dT, o);
      dTs   += __shfl_xor(dTs, o);
    }
    if (lane == 0) {
      diag[i] = dDiag;
      float posMean = (dTs - dDiag) / fmaxf((float)(m - 1), 1.f);
      float negMean = (dT - dTs) / fmaxf((float)(BB - m), 1.f);
      float t = fmaxf(negMean - posMean + MARGIN, 0.f);
      tri[i] = (m >= 2 && m <= BB - 1) ? t : 0.f;
    }
    return;
  }

  // ---------------- k5 path ----------------
  int s = blockIdx.x >> 3;
  int sub = blockIdx.x & 7;
  int rt0 = sub >> 1;   // stride 4
  int ct0 = sub & 1;    // stride 2
  int m = counts[s];
  int g0 = offsets[s];
  int lane = tid & 63, wv = tid >> 6;
  int quad = lane >> 4, cl = lane & 15;

  for (int rt = rt0; rt * 64 < m; rt += 4) {
    for (int ct = ct0; ct * 128 < m; ct += 2) {
      float4v acc[8];
      #pragma unroll
      for (int cf = 0; cf < 8; ++cf) acc[cf] = (float4v){0.f, 0.f, 0.f, 0.f};

      for (int kc = 0; kc < 4; ++kc) {
        __syncthreads();
        #pragma unroll
        for (int p = 0; p < 6; ++p) {
          int u = p * 256 + tid;
          int isB = u >= 512;
          int v = isB ? (u - 512) : u;
          int row = v >> 3;            // A: 0..63 ; B: 0..127
          int subu = v & 7;
          int ksl = subu >> 2, q = subu & 3;
          int d0 = kc * 64 + ksl * 32 + q * 8;
          int idx = isB ? (ct * 128 + row) : (rt * 64 + row);
          uint4v val = (uint4v){0u, 0u, 0u, 0u};
          if (idx < m) {
            const float* src = (isB ? tx : sp) + memberList[g0 + idx] * DD + d0;
            float4 f0 = *reinterpret_cast<const float4*>(src);
            float4 f1 = *reinterpret_cast<const float4*>(src + 4);
            val = pack8(f0, f1);
          }
          int qs = q ^ ((row >> 1) & 3);  // bank swizzle
          int dst = isB ? (512 + (ksl * 128 + row) * 4 + qs)
                        : ((ksl * 64 + row) * 4 + qs);
          lds5[dst] = val;
        }
        __syncthreads();
        #pragma unroll
        for (int ksl = 0; ksl < 2; ++ksl) {
          int ar = wv * 16 + cl;
          half8 a = __builtin_bit_cast(half8,
              lds5[(ksl * 64 + ar) * 4 + (quad ^ ((ar >> 1) & 3))]);
          #pragma unroll
          for (int cf = 0; cf < 8; ++cf) {
            int br = cf * 16 + cl;
            half8 b = __builtin_bit_cast(half8,
                lds5[512 + (ksl * 128 + br) * 4 + (quad ^ ((br >> 1) & 3))]);
            acc[cf] = __builtin_amdgcn_mfma_f32_16x16x32_f16(a, b, acc[cf], 0, 0, 0);
          }
        }
      }

      // epilogue: masked exp, row/col sums
      int riBase = rt * 64 + wv * 16 + quad * 4;  // + reg
      float rowAcc[4] = {0.f, 0.f, 0.f, 0.f};
      #pragma unroll
      for (int cf = 0; cf < 8; ++cf) {
        int ci = ct * 128 + cf * 16 + cl;
        bool cv = ci < m;
        float colAcc = 0.f;
        #pragma unroll
        for (int reg = 0; reg < 4; ++reg) {
          bool rv = (riBase + reg) < m;
          float e = (rv && cv) ? __expf(acc[cf][reg] * (1.f / TAU)) : 0.f;
          rowAcc[reg] += e;
          colAcc += e;
        }
        colAcc += __shfl_xor(colAcc, 16);
        colAcc += __shfl_xor(colAcc, 32);
        if (quad == 0 && cv) atomicAdd(&lseCol[g0 + ci], colAcc);
      }
      #pragma unroll
      for (int reg = 0; reg < 4; ++reg) {
        float v = rowAcc[reg];
        v += __shfl_xor(v, 1);
        v += __shfl_xor(v, 2);
        v += __shfl_xor(v, 4);
        v += __shfl_xor(v, 8);
        if (cl == 0 && (riBase + reg) < m) atomicAdd(&lseRow[g0 + riBase + reg], v);
      }
    }
  }
}

// ---- k67: InfoNCE gather + tri reduction + final combine (arrival counter) ----
__global__ void k67_info(const int* __restrict__ memberList, const int* __restrict__ ids,
                         const int* __restrict__ counts, const float* __restrict__ lseRow,
                         const float* __restrict__ lseCol, const float* __restrict__ diag,
                         const float* __restrict__ tri, float* scalars, float* out) {
  __shared__ float red[8];  // [0..3]=info per wave, [4..7]=tri per wave
  int g = blockIdx.x * blockDim.x + threadIdx.x;
  int i = memberList[g];
  int s = ids[i];
  int m = counts[s];
  float tt = tri[i];
  float term = 0.f;
  if (m >= 2) {
    term = (__logf(lseRow[g]) + __logf(lseCol[g]) - 2.f * diag[i] * (1.f / TAU)) /
           (2.f * (float)m);
  }
  #pragma unroll
  for (int o = 1; o < 64; o <<= 1) {
    term += __shfl_xor(term, o);
    tt += __shfl_xor(tt, o);
  }
  int wv = threadIdx.x >> 6, lane = threadIdx.x & 63;
  if (lane == 0) { red[wv] = term; red[4 + wv] = tt; }
  __syncthreads();
  if (threadIdx.x == 0) {
    atomicAdd(&scalars[1], red[0] + red[1] + red[2] + red[3]);
    atomicAdd(&scalars[0], red[4] + red[5] + red[6] + red[7]);
    __threadfence();
    int old = atomicAdd((int*)&scalars[4], 1);
    if (old == (int)gridDim.x - 1) {
      float info = atomicAdd(&scalars[1], 0.f);  // atomic load (L2-coherent)
      float trs  = atomicAdd(&scalars[0], 0.f);
      out[0] = info / fmaxf(scalars[2], 1.f) + trs / fmaxf(scalars[3], 1.f);
    }
  }
}

extern "C" void kernel_launch(void* const* d_in, const int* in_sizes, int n_in,
                              void* d_out, int out_size, void* d_ws, size_t ws_size,
                              hipStream_t stream) {
  const float* sp = (const float*)d_in[0];
  const float* tx = (const float*)d_in[1];
  const int* ids = (const int*)d_in[2];
  float* out = (float*)d_out;

  char* ws = (char*)d_ws;
  float* scalars = (float*)(ws + WS_SCALARS);
  int* counts = (int*)(ws + WS_COUNTS);
  int* offsets = (int*)(ws + WS_OFFSETS);
  float* lseRow = (float*)(ws + WS_LSEROW);
  float* lseCol = (float*)(ws + WS_LSECOL);
  float* Ts = (float*)(ws + WS_TS);
  float* T = (float*)(ws + WS_T);
  float* diag = (float*)(ws + WS_DIAG);
  int* memberList = (int*)(ws + WS_MEMBER);
  float* tri = (float*)(ws + WS_TRI);

  k1_all<<<1, 1024, 0, stream>>>(ids, ws, counts, offsets, memberList, scalars);
  k2_ts<<<dim3(NSPEC, 8), 256, 0, stream>>>(tx, counts, offsets, memberList, Ts, T,
                                            scalars);
  k45<<<NB45, 256, 0, stream>>>(sp, tx, ids, counts, offsets, memberList, Ts, T,
                                diag, tri, lseRow, lseCol);
  k67_info<<<BB / 256, 256, 0, stream>>>(memberList, ids, counts, lseRow, lseCol,
                                         diag, tri, scalars, out);
}

// Round 7
// 111.305 us; speedup vs baseline: 1.3856x; 1.3856x over previous
//
#include <hip/hip_runtime.h>
#include <hip/hip_fp16.h>

#define TAU 0.07f
#define MARGIN 0.2f
#define NSPEC 64
#define BB 8192
#define DD 256

// ---------------- ws layout (bytes) ----------------
// zeroed-by-k1 region: [0, 133120)
//   0      float scalars[8] [0]=triSum [1]=infoSum [2]=n_valid [3]=n_valid_i
//                           [4]=doneCnt(int,k67)
//   288    int   counts[64]
//   544    int   offsets[64]
//   1024   float lseRow[B]
//   33792  float lseCol[B]
//   66560  float Ts[64*256]   (atomic-accumulated)
//   132096 float T[256]
// unzeroed:
//   133632 float diag[B]
//   166400 int   memberList[B]
//   199168 float tri[B]
#define WS_SCALARS   0
#define WS_COUNTS    288
#define WS_OFFSETS   544
#define WS_LSEROW    1024
#define WS_LSECOL    33792
#define WS_TS        66560
#define WS_T         132096
#define WS_ZERO_BYTES 133120   // 8320 float4
#define WS_DIAG      133632
#define WS_MEMBER    166400
#define WS_TRI       199168

typedef _Float16 half8 __attribute__((ext_vector_type(8)));
typedef float float4v __attribute__((ext_vector_type(4)));
typedef unsigned int uint4v __attribute__((ext_vector_type(4)));

#define NB5 512          // k5-role blocks in fused k45 (species x 4 rt x 2 ct)
#define NB45 (NB5 + BB/4)

__device__ __forceinline__ uint4v pack8(float4 a, float4 b) {
  half8 h;
  h[0] = (_Float16)a.x; h[1] = (_Float16)a.y; h[2] = (_Float16)a.z; h[3] = (_Float16)a.w;
  h[4] = (_Float16)b.x; h[5] = (_Float16)b.y; h[6] = (_Float16)b.z; h[7] = (_Float16)b.w;
  return __builtin_bit_cast(uint4v, h);
}

// ---- k1_all: zero accumulators + counts + scan + scatter + valid-counts ----
__global__ void k1_all(const int* __restrict__ ids, char* ws, int* counts_g,
                       int* offsets_g, int* memberList, float* scalars) {
  __shared__ int cnt[NSPEC];
  __shared__ int off[NSPEC];
  int tid = threadIdx.x;
  float4* z = (float4*)ws;
  float4 z4 = make_float4(0.f, 0.f, 0.f, 0.f);
  for (int u = tid; u < WS_ZERO_BYTES / 16; u += 1024) z[u] = z4;
  if (tid < NSPEC) cnt[tid] = 0;
  __syncthreads();
  int myS[8], myP[8];
  #pragma unroll
  for (int r = 0; r < 8; ++r) {
    int i = r * 1024 + tid;
    int s = ids[i];
    myS[r] = s;
    myP[r] = atomicAdd(&cnt[s], 1);
  }
  __syncthreads();
  if (tid < NSPEC) {  // exactly wave 0
    int o = 0;
    for (int t = 0; t < NSPEC; ++t) o += (t < tid) ? cnt[t] : 0;
    off[tid] = o;
    offsets_g[tid] = o;
    int c = cnt[tid];
    counts_g[tid] = c;
    unsigned long long bv = __ballot(c >= 2);
    float nvi = (c >= 2 && c <= BB - 1) ? (float)c : 0.f;
    for (int o2 = 1; o2 < 64; o2 <<= 1) nvi += __shfl_xor(nvi, o2);
    if (tid == 0) {
      scalars[2] = (float)__popcll(bv);
      scalars[3] = nvi;
    }
  }
  __syncthreads();
  #pragma unroll
  for (int r = 0; r < 8; ++r) {
    int i = r * 1024 + tid;
    memberList[off[myS[r]] + myP[r]] = i;
  }
}

// ---- k2: per-species text sums Ts[s][d], 8 slices + atomic merge (NO fence) ----
__global__ void k2_ts(const float* __restrict__ tx, const int* __restrict__ counts,
                      const int* __restrict__ offsets, const int* __restrict__ memberList,
                      float* Ts) {
  int s = blockIdx.x, r = blockIdx.y;
  int m = counts[s], g0 = offsets[s];
  int k0 = (m * r) >> 3, k1 = (m * (r + 1)) >> 3;
  if (k0 >= k1) return;
  int d = threadIdx.x;
  float acc = 0.f;
  for (int k = k0; k < k1; ++k) acc += tx[memberList[g0 + k] * DD + d];
  atomicAdd(&Ts[s * DD + d], acc);
}

// ---- k2b: global text sum T[d] (single block, clean dispatch boundary) ----
__global__ void k2b_t(const float* __restrict__ Ts, float* T) {
  int d = threadIdx.x;
  float acc = 0.f;
  for (int s = 0; s < NSPEC; ++s) acc += Ts[s * DD + d];
  T[d] = acc;
}

// ---- k45: fused. Blocks [0,NB5): per-species MFMA sum-of-exp.
//           Blocks [NB5,NB45): per-row diag/triplet (one wave per row). ----
__global__ void k45(const float* __restrict__ sp, const float* __restrict__ tx,
                    const int* __restrict__ ids, const int* __restrict__ counts,
                    const int* __restrict__ offsets, const int* __restrict__ memberList,
                    const float* __restrict__ Ts, const float* __restrict__ T,
                    float* diag, float* tri, float* lseRow, float* lseCol) {
  __shared__ uint4v lds5[1536];  // A: [0,512) ; B: [512,1536)  (24 KB, k5 path only)
  int tid = threadIdx.x;

  if (blockIdx.x >= NB5) {
    // ---------------- k4 path: 4 rows per block, one wave per row ----------------
    int gt = (blockIdx.x - NB5) * 256 + tid;
    int i = gt >> 6, lane = gt & 63;
    float4 a = *reinterpret_cast<const float4*>(sp + i * DD + lane * 4);
    float4 b = *reinterpret_cast<const float4*>(tx + i * DD + lane * 4);
    float4 tv = *reinterpret_cast<const float4*>(T + lane * 4);
    int s = ids[i];
    int m = counts[s];
    float4 c = *reinterpret_cast<const float4*>(Ts + s * DD + lane * 4);
    float dDiag = a.x * b.x + a.y * b.y + a.z * b.z + a.w * b.w;
    float dT    = a.x * tv.x + a.y * tv.y + a.z * tv.z + a.w * tv.w;
    float dTs   = a.x * c.x + a.y * c.y + a.z * c.z + a.w * c.w;
    #pragma unroll
    for (int o = 1; o < 64; o <<= 1) {
      dDiag += __shfl_xor(dDiag, o);
      dT    += __shfl_xor(dT, o);
      dTs   += __shfl_xor(dTs, o);
    }
    if (lane == 0) {
      diag[i] = dDiag;
      float posMean = (dTs - dDiag) / fmaxf((float)(m - 1), 1.f);
      float negMean = (dT - dTs) / fmaxf((float)(BB - m), 1.f);
      float t = fmaxf(negMean - posMean + MARGIN, 0.f);
      tri[i] = (m >= 2 && m <= BB - 1) ? t : 0.f;
    }
    return;
  }

  // ---------------- k5 path ----------------
  int s = blockIdx.x >> 3;
  int sub = blockIdx.x & 7;
  int rt0 = sub >> 1;   // stride 4
  int ct0 = sub & 1;    // stride 2
  int m = counts[s];
  int g0 = offsets[s];
  int lane = tid & 63, wv = tid >> 6;
  int quad = lane >> 4, cl = lane & 15;

  for (int rt = rt0; rt * 64 < m; rt += 4) {
    for (int ct = ct0; ct * 128 < m; ct += 2) {
      float4v acc[8];
      #pragma unroll
      for (int cf = 0; cf < 8; ++cf) acc[cf] = (float4v){0.f, 0.f, 0.f, 0.f};

      for (int kc = 0; kc < 4; ++kc) {
        __syncthreads();
        #pragma unroll
        for (int p = 0; p < 6; ++p) {
          int u = p * 256 + tid;
          int isB = u >= 512;
          int v = isB ? (u - 512) : u;
          int row = v >> 3;            // A: 0..63 ; B: 0..127
          int subu = v & 7;
          int ksl = subu >> 2, q = subu & 3;
          int d0 = kc * 64 + ksl * 32 + q * 8;
          int idx = isB ? (ct * 128 + row) : (rt * 64 + row);
          uint4v val = (uint4v){0u, 0u, 0u, 0u};
          if (idx < m) {
            const float* src = (isB ? tx : sp) + memberList[g0 + idx] * DD + d0;
            float4 f0 = *reinterpret_cast<const float4*>(src);
            float4 f1 = *reinterpret_cast<const float4*>(src + 4);
            val = pack8(f0, f1);
          }
          int qs = q ^ ((row >> 1) & 3);  // bank swizzle
          int dst = isB ? (512 + (ksl * 128 + row) * 4 + qs)
                        : ((ksl * 64 + row) * 4 + qs);
          lds5[dst] = val;
        }
        __syncthreads();
        #pragma unroll
        for (int ksl = 0; ksl < 2; ++ksl) {
          int ar = wv * 16 + cl;
          half8 a = __builtin_bit_cast(half8,
              lds5[(ksl * 64 + ar) * 4 + (quad ^ ((ar >> 1) & 3))]);
          #pragma unroll
          for (int cf = 0; cf < 8; ++cf) {
            int br = cf * 16 + cl;
            half8 b = __builtin_bit_cast(half8,
                lds5[512 + (ksl * 128 + br) * 4 + (quad ^ ((br >> 1) & 3))]);
            acc[cf] = __builtin_amdgcn_mfma_f32_16x16x32_f16(a, b, acc[cf], 0, 0, 0);
          }
        }
      }

      // epilogue: masked exp, row/col sums
      int riBase = rt * 64 + wv * 16 + quad * 4;  // + reg
      float rowAcc[4] = {0.f, 0.f, 0.f, 0.f};
      #pragma unroll
      for (int cf = 0; cf < 8; ++cf) {
        int ci = ct * 128 + cf * 16 + cl;
        bool cv = ci < m;
        float colAcc = 0.f;
        #pragma unroll
        for (int reg = 0; reg < 4; ++reg) {
          bool rv = (riBase + reg) < m;
          float e = (rv && cv) ? __expf(acc[cf][reg] * (1.f / TAU)) : 0.f;
          rowAcc[reg] += e;
          colAcc += e;
        }
        colAcc += __shfl_xor(colAcc, 16);
        colAcc += __shfl_xor(colAcc, 32);
        if (quad == 0 && cv) atomicAdd(&lseCol[g0 + ci], colAcc);
      }
      #pragma unroll
      for (int reg = 0; reg < 4; ++reg) {
        float v = rowAcc[reg];
        v += __shfl_xor(v, 1);
        v += __shfl_xor(v, 2);
        v += __shfl_xor(v, 4);
        v += __shfl_xor(v, 8);
        if (cl == 0 && (riBase + reg) < m) atomicAdd(&lseRow[g0 + riBase + reg], v);
      }
    }
  }
}

// ---- k67: InfoNCE gather + tri reduction + final combine.
//      Ordering via s_waitcnt(0) (drain this wave's atomics) — NO threadfence
//      (device-scope fence emits buffer_wbl2 = L2 writeback storm). ----
__global__ void k67_info(const int* __restrict__ memberList, const int* __restrict__ ids,
                         const int* __restrict__ counts, const float* __restrict__ lseRow,
                         const float* __restrict__ lseCol, const float* __restrict__ diag,
                         const float* __restrict__ tri, float* scalars, float* out) {
  __shared__ float red[8];  // [0..3]=info per wave, [4..7]=tri per wave
  int g = blockIdx.x * blockDim.x + threadIdx.x;
  int i = memberList[g];
  int s = ids[i];
  int m = counts[s];
  float tt = tri[i];
  float term = 0.f;
  if (m >= 2) {
    term = (__logf(lseRow[g]) + __logf(lseCol[g]) - 2.f * diag[i] * (1.f / TAU)) /
           (2.f * (float)m);
  }
  #pragma unroll
  for (int o = 1; o < 64; o <<= 1) {
    term += __shfl_xor(term, o);
    tt += __shfl_xor(tt, o);
  }
  int wv = threadIdx.x >> 6, lane = threadIdx.x & 63;
  if (lane == 0) { red[wv] = term; red[4 + wv] = tt; }
  __syncthreads();
  if (threadIdx.x == 0) {
    atomicAdd(&scalars[1], red[0] + red[1] + red[2] + red[3]);
    atomicAdd(&scalars[0], red[4] + red[5] + red[6] + red[7]);
    __builtin_amdgcn_s_waitcnt(0);  // both atomics completed at coherence point
    int old = atomicAdd((int*)&scalars[4], 1);
    if (old == (int)gridDim.x - 1) {
      float info = atomicAdd(&scalars[1], 0.f);  // atomic load (coherent)
      float trs  = atomicAdd(&scalars[0], 0.f);
      out[0] = info / fmaxf(scalars[2], 1.f) + trs / fmaxf(scalars[3], 1.f);
    }
  }
}

extern "C" void kernel_launch(void* const* d_in, const int* in_sizes, int n_in,
                              void* d_out, int out_size, void* d_ws, size_t ws_size,
                              hipStream_t stream) {
  const float* sp = (const float*)d_in[0];
  const float* tx = (const float*)d_in[1];
  const int* ids = (const int*)d_in[2];
  float* out = (float*)d_out;

  char* ws = (char*)d_ws;
  float* scalars = (float*)(ws + WS_SCALARS);
  int* counts = (int*)(ws + WS_COUNTS);
  int* offsets = (int*)(ws + WS_OFFSETS);
  float* lseRow = (float*)(ws + WS_LSEROW);
  float* lseCol = (float*)(ws + WS_LSECOL);
  float* Ts = (float*)(ws + WS_TS);
  float* T = (float*)(ws + WS_T);
  float* diag = (float*)(ws + WS_DIAG);
  int* memberList = (int*)(ws + WS_MEMBER);
  float* tri = (float*)(ws + WS_TRI);

  k1_all<<<1, 1024, 0, stream>>>(ids, ws, counts, offsets, memberList, scalars);
  k2_ts<<<dim3(NSPEC, 8), 256, 0, stream>>>(tx, counts, offsets, memberList, Ts);
  k2b_t<<<1, 256, 0, stream>>>(Ts, T);
  k45<<<NB45, 256, 0, stream>>>(sp, tx, ids, counts, offsets, memberList, Ts, T,
                                diag, tri, lseRow, lseCol);
  k67_info<<<BB / 256, 256, 0, stream>>>(memberList, ids, counts, lseRow, lseCol,
                                         diag, tri, scalars, out);
}